// Round 9
// baseline (279.484 us; speedup 1.0000x reference)
//
#include <hip/hip_runtime.h>

#define SMOOTH 1e-8f

typedef float f32x4 __attribute__((ext_vector_type(4)));

// Fixed problem shape: [N, C, Z, X, Y] = [4, 2, 160, 160, 160]
constexpr int NROWS = 8000;            // per-(16^3 block, channel) rows
constexpr int WG1   = 3200;            // one-wave quarter-slab workgroups

__global__ void zero_out_kernel(float* out) { out[0] = 0.0f; }

// Kernel 1: one WAVE per (n,c,zz,xx,q4) quarter-slab = 4 z-planes, each
// plane-row = 640 contiguous f4 (10 KB). Ping-pong double-batch: issue 20
// nt loads of plane p+1 before consuming plane p, so >=20 loads stay in
// flight through every consume; single drain + tail per 160 KB.
// Binning algebra (verified R7/R8): load k, lane -> f4 slot
// j = (lane + 24k) mod 40; yy = 2r + b, r = j>>3 (period 5 in k, lane-only
// mapping rr[m]), b = (lane>>2)&1. Accumulating across planes is valid
// because rr[] is plane-independent.
__global__ __launch_bounds__(64, 2)
void partial_kernel(const float* __restrict__ pred,
                    const float* __restrict__ gt,
                    float* __restrict__ wsq)
{
    int wg = blockIdx.x;
    const int q4 = wg & 3;  wg >>= 2;
    const int c  = wg & 1;  wg >>= 1;
    const int xx = wg % 10; wg /= 10;
    const int zz = wg % 10;
    const int n  = wg / 10;

    const int lane = threadIdx.x;               // 64-thread WG = 1 wave
    const int z0   = zz * 16 + q4 * 4;          // first of this wave's 4 planes

    // f4 base of plane-row for plane z0: 16 x-lines * 40 f4 contiguous
    const long pb0 = ((long)((n * 2 + c) * 160 + z0) * 160 + xx * 16) * 40L;
    constexpr long PSTR = 6400;                 // z-plane stride in f4

    const f32x4* p4 = reinterpret_cast<const f32x4*>(pred) + pb0 + lane;
    const f32x4* g4 = reinterpret_cast<const f32x4*>(gt)  + pb0 + lane;

    f32x4 PA[10], GA[10], PB[10], GB[10];
    float aS[5] = {0,0,0,0,0}, aG[5] = {0,0,0,0,0}, aP[5] = {0,0,0,0,0};

#define ISSUE(Pbuf, Gbuf, plane)                                              \
    _Pragma("unroll")                                                         \
    for (int k = 0; k < 10; ++k) {                                            \
        Pbuf[k] = __builtin_nontemporal_load(p4 + (plane) * PSTR + k * 64);   \
        Gbuf[k] = __builtin_nontemporal_load(g4 + (plane) * PSTR + k * 64);   \
    }

#define CONSUME(Pbuf, Gbuf)                                                   \
    _Pragma("unroll")                                                         \
    for (int k = 0; k < 10; ++k) {                                            \
        const int m = k % 5;                                                  \
        const f32x4 p = Pbuf[k], g = Gbuf[k];                                 \
        aS[m] += (p.x + p.y) + (p.z + p.w);                                   \
        aG[m] += (g.x + g.y) + (g.z + g.w);                                   \
        aP[m] += p.x * g.x + p.y * g.y + p.z * g.z + p.w * g.w;               \
    }

    ISSUE(PA, GA, 0)
    __builtin_amdgcn_sched_barrier(0);
    ISSUE(PB, GB, 1)
    __builtin_amdgcn_sched_barrier(0);
    CONSUME(PA, GA)                 // plane 0; B stays in flight
    ISSUE(PA, GA, 2)
    __builtin_amdgcn_sched_barrier(0);
    CONSUME(PB, GB)                 // plane 1; A(2) in flight
    ISSUE(PB, GB, 3)
    __builtin_amdgcn_sched_barrier(0);
    CONSUME(PA, GA)                 // plane 2; B(3) in flight
    CONSUME(PB, GB)                 // plane 3
#undef ISSUE
#undef CONSUME

    // ---- rotate m-indexed triplets into r-indexed (yy = 2r + b) ----
    int rr[5];
    #pragma unroll
    for (int m = 0; m < 5; ++m)
        rr[m] = ((lane + 24 * m) % 40) >> 3;    // runtime value, static index

    float bS[5], bG[5], bP[5];
    #pragma unroll
    for (int r = 0; r < 5; ++r) {
        float s = 0.f, g = 0.f, p = 0.f;
        #pragma unroll
        for (int m = 0; m < 5; ++m) {
            const bool hit = (rr[m] == r);      // exactly one m matches
            s += hit ? aS[m] : 0.f;
            g += hit ? aG[m] : 0.f;
            p += hit ? aP[m] : 0.f;
        }
        bS[r] = s; bG[r] = g; bP[r] = p;
    }

    // ---- xor-reduce over lane bits {0,1,3,4,5}: preserves b = bit2 ----
    #pragma unroll
    for (int r = 0; r < 5; ++r) {
        #pragma unroll
        for (int d = 0; d < 5; ++d) {
            const int msk = (d < 2) ? (1 << d) : (1 << (d + 1));  // 1,2,8,16,32
            bS[r] += __shfl_xor(bS[r], msk, 64);
            bG[r] += __shfl_xor(bG[r], msk, 64);
            bP[r] += __shfl_xor(bP[r], msk, 64);
        }
    }

    __shared__ float red[2][15];                // [b][r*3+comp]
    const int b = (lane >> 2) & 1;
    if ((lane & 59) == 0) {                     // lanes 0 (b=0) and 4 (b=1)
        #pragma unroll
        for (int r = 0; r < 5; ++r) {
            red[b][r * 3 + 0] = bS[r];
            red[b][r * 3 + 1] = bG[r];
            red[b][r * 3 + 2] = bP[r];
        }
    }
    __syncthreads();

    if (lane < 30) {
        const int yy   = lane / 3;
        const int comp = lane - yy * 3;
        const int bb = yy & 1, r = yy >> 1;
        const float val = red[bb][r * 3 + comp];
        const int row = (((n * 10 + zz) * 10 + xx) * 10 + yy) * 2 + c;
        wsq[(row * 4 + q4) * 3 + comp] = val;   // distinct slot, no atomic
    }
}

// Kernel 2: 32 WGs — combine quarters, nonlinear term, per-wave atomic.
__global__ __launch_bounds__(256)
void finalize_kernel(const float* __restrict__ wsq,
                     const float* __restrict__ a_p,
                     const float* __restrict__ b_p,
                     float* __restrict__ out)
{
    const int r = blockIdx.x * 256 + threadIdx.x;
    float term = 0.f;
    if (r < NROWS) {
        const float4 w0 = *reinterpret_cast<const float4*>(wsq + r * 12);
        const float4 w1 = *reinterpret_cast<const float4*>(wsq + r * 12 + 4);
        const float4 w2 = *reinterpret_cast<const float4*>(wsq + r * 12 + 8);
        const float SP  = w0.x + w0.w + w1.z + w2.y;
        const float SG  = w0.y + w1.x + w1.w + w2.z;
        const float SGP = w0.z + w1.y + w2.x + w2.w;

        const float tp = SGP;
        const float fn = SG - SGP;
        const float fp = SP - SGP;
        const float a = a_p[0], b = b_p[0];
        const float denom = fp + fn + SMOOTH;
        const float alpha = a + b * ((fp + SMOOTH) / denom);
        const float beta  = a + b * ((fn + SMOOTH) / denom);
        term = 1.f - (tp + SMOOTH) / (tp + alpha * fp + beta * fn + SMOOTH);
    }
    #pragma unroll
    for (int d = 32; d > 0; d >>= 1) term += __shfl_down(term, d, 64);
    if ((threadIdx.x & 63) == 0) atomicAdd(out, term);
}

extern "C" void kernel_launch(void* const* d_in, const int* in_sizes, int n_in,
                              void* d_out, int out_size, void* d_ws, size_t ws_size,
                              hipStream_t stream)
{
    const float* pred = (const float*)d_in[0];
    const float* gt   = (const float*)d_in[1];
    const float* a_p  = (const float*)d_in[2];
    const float* b_p  = (const float*)d_in[3];
    float* out = (float*)d_out;
    float* wsq = (float*)d_ws;   // 8000 rows * 4 quarters * 3 sums = 384 KB

    zero_out_kernel<<<1, 1, 0, stream>>>(out);
    partial_kernel<<<WG1, 64, 0, stream>>>(pred, gt, wsq);
    finalize_kernel<<<(NROWS + 255) / 256, 256, 0, stream>>>(wsq, a_p, b_p, out);
}

// Round 10
// 252.993 us; speedup vs baseline: 1.1047x; 1.1047x over previous
//
#include <hip/hip_runtime.h>

#define SMOOTH 1e-8f

typedef float f32x4 __attribute__((ext_vector_type(4)));

// Fixed problem shape: [N, C, Z, X, Y] = [4, 2, 160, 160, 160]
constexpr int NROWS = 8000;            // per-(16^3 block, channel) rows
constexpr int WG1   = 3200;            // quarter-slab workgroups

// Kernel 1 (= round-7 best, 253us total): quarter-slab (n,c,zz,xx, 4
// z-planes). Each WAVE owns one z-plane slab row = 640 contiguous f4
// (10 KB): 10 perfectly unit-stride 1KB wave loads per tensor, all
// non-temporal (L1 bypass), issued in one batch before any consumption.
// Binning algebra (verified R7/R8/R9): load k, lane -> f4 slot
// j = (lane + 24k) mod 40, period 5 in k => 5 static (S,G,P) triplets;
// yy = 2r + b, r = rr[m] (lane-only), b = (lane>>2)&1.
__global__ __launch_bounds__(256, 4)
void partial_kernel(const float* __restrict__ pred,
                    const float* __restrict__ gt,
                    float* __restrict__ wsq)
{
    int wg = blockIdx.x;
    const int q4 = wg & 3;  wg >>= 2;
    const int c  = wg & 1;  wg >>= 1;
    const int xx = wg % 10; wg /= 10;
    const int zz = wg % 10;
    const int n  = wg / 10;

    const int t    = threadIdx.x;
    const int lane = t & 63;
    const int wave = t >> 6;
    const int z    = zz * 16 + q4 * 4 + wave;   // one z-plane per wave

    const long pb = ((long)((n * 2 + c) * 160 + z) * 160 + xx * 16) * 40L;

    const f32x4* p4 = reinterpret_cast<const f32x4*>(pred) + pb + lane;
    const f32x4* g4 = reinterpret_cast<const f32x4*>(gt)  + pb + lane;

    // ---- issue phase: 20 unit-stride 1KB nt loads, no consumption ----
    f32x4 P[10], G[10];
    #pragma unroll
    for (int k = 0; k < 10; ++k) {
        P[k] = __builtin_nontemporal_load(p4 + k * 64);
        G[k] = __builtin_nontemporal_load(g4 + k * 64);
    }

    // ---- consume (FIFO): 5 static triplets, m = k mod 5 ----
    float aS[5] = {0, 0, 0, 0, 0};
    float aG[5] = {0, 0, 0, 0, 0};
    float aP[5] = {0, 0, 0, 0, 0};
    #pragma unroll
    for (int k = 0; k < 10; ++k) {
        const int m = k % 5;                    // compile-time
        const f32x4 p = P[k], g = G[k];
        aS[m] += (p.x + p.y) + (p.z + p.w);
        aG[m] += (g.x + g.y) + (g.z + g.w);
        aP[m] += p.x * g.x + p.y * g.y + p.z * g.z + p.w * g.w;
    }

    // ---- rotate m-indexed triplets into r-indexed (yy = 2r + b) ----
    int rr[5];
    #pragma unroll
    for (int m = 0; m < 5; ++m)
        rr[m] = ((lane + 24 * m) % 40) >> 3;    // runtime value, static index

    float bS[5], bG[5], bP[5];
    #pragma unroll
    for (int r = 0; r < 5; ++r) {
        float s = 0.f, g = 0.f, p = 0.f;
        #pragma unroll
        for (int m = 0; m < 5; ++m) {
            const bool hit = (rr[m] == r);      // exactly one m matches
            s += hit ? aS[m] : 0.f;
            g += hit ? aG[m] : 0.f;
            p += hit ? aP[m] : 0.f;
        }
        bS[r] = s; bG[r] = g; bP[r] = p;
    }

    // ---- xor-reduce over lane bits {0,1,3,4,5}: preserves b = bit2 ----
    #pragma unroll
    for (int r = 0; r < 5; ++r) {
        #pragma unroll
        for (int d = 0; d < 5; ++d) {
            const int msk = (d < 2) ? (1 << d) : (1 << (d + 1));  // 1,2,8,16,32
            bS[r] += __shfl_xor(bS[r], msk, 64);
            bG[r] += __shfl_xor(bG[r], msk, 64);
            bP[r] += __shfl_xor(bP[r], msk, 64);
        }
    }

    __shared__ float red[4][2][15];             // [wave][b][r*3+comp]
    const int b = (lane >> 2) & 1;
    if ((lane & 59) == 0) {                     // lanes 0 (b=0) and 4 (b=1)
        #pragma unroll
        for (int r = 0; r < 5; ++r) {
            red[wave][b][r * 3 + 0] = bS[r];
            red[wave][b][r * 3 + 1] = bG[r];
            red[wave][b][r * 3 + 2] = bP[r];
        }
    }
    __syncthreads();

    if (t < 30) {
        const int yy   = t / 3;
        const int comp = t - yy * 3;
        const int bb = yy & 1, r = yy >> 1;
        const float val = red[0][bb][r * 3 + comp] + red[1][bb][r * 3 + comp] +
                          red[2][bb][r * 3 + comp] + red[3][bb][r * 3 + comp];
        const int row = (((n * 10 + zz) * 10 + xx) * 10 + yy) * 2 + c;
        wsq[(row * 4 + q4) * 3 + comp] = val;   // distinct slot, no atomic
    }
}

// Kernel 2a: 32 WGs — combine quarters, nonlinear term, per-WG partial
// (non-atomic; stage-2 buffer lives past the 96000-float wsq region).
__global__ __launch_bounds__(256)
void finalize1_kernel(const float* __restrict__ wsq,
                      const float* __restrict__ a_p,
                      const float* __restrict__ b_p,
                      float* __restrict__ part)
{
    const int r = blockIdx.x * 256 + threadIdx.x;
    float term = 0.f;
    if (r < NROWS) {
        const float4 w0 = *reinterpret_cast<const float4*>(wsq + r * 12);
        const float4 w1 = *reinterpret_cast<const float4*>(wsq + r * 12 + 4);
        const float4 w2 = *reinterpret_cast<const float4*>(wsq + r * 12 + 8);
        const float SP  = w0.x + w0.w + w1.z + w2.y;
        const float SG  = w0.y + w1.x + w1.w + w2.z;
        const float SGP = w0.z + w1.y + w2.x + w2.w;

        const float tp = SGP;
        const float fn = SG - SGP;
        const float fp = SP - SGP;
        const float a = a_p[0], b = b_p[0];
        const float denom = fp + fn + SMOOTH;
        const float alpha = a + b * ((fp + SMOOTH) / denom);
        const float beta  = a + b * ((fn + SMOOTH) / denom);
        term = 1.f - (tp + SMOOTH) / (tp + alpha * fp + beta * fn + SMOOTH);
    }
    #pragma unroll
    for (int d = 32; d > 0; d >>= 1) term += __shfl_down(term, d, 64);

    __shared__ float wsum[4];
    if ((threadIdx.x & 63) == 0) wsum[threadIdx.x >> 6] = term;
    __syncthreads();
    if (threadIdx.x == 0)
        part[blockIdx.x] = wsum[0] + wsum[1] + wsum[2] + wsum[3];
}

// Kernel 2b: one wave sums the 32 partials.
__global__ __launch_bounds__(64)
void finalize2_kernel(const float* __restrict__ part, float* __restrict__ out)
{
    const int t = threadIdx.x;
    float v = (t < 32) ? part[t] : 0.f;
    #pragma unroll
    for (int d = 32; d > 0; d >>= 1) v += __shfl_down(v, d, 64);
    if (t == 0) out[0] = v;
}

extern "C" void kernel_launch(void* const* d_in, const int* in_sizes, int n_in,
                              void* d_out, int out_size, void* d_ws, size_t ws_size,
                              hipStream_t stream)
{
    const float* pred = (const float*)d_in[0];
    const float* gt   = (const float*)d_in[1];
    const float* a_p  = (const float*)d_in[2];
    const float* b_p  = (const float*)d_in[3];
    float* out  = (float*)d_out;
    float* wsq  = (float*)d_ws;          // 8000 rows * 4 quarters * 3 = 96000 f
    float* part = wsq + 96000;           // 32 stage-2 partials

    partial_kernel<<<WG1, 256, 0, stream>>>(pred, gt, wsq);
    finalize1_kernel<<<(NROWS + 255) / 256, 256, 0, stream>>>(wsq, a_p, b_p, part);
    finalize2_kernel<<<1, 64, 0, stream>>>(part, out);
}